// Round 9
// baseline (252.608 us; speedup 1.0000x reference)
//
#include <hip/hip_runtime.h>
#include <hip/hip_bf16.h>
#include <cstdint>
#include <cstddef>

typedef __bf16 bf16_t;
typedef bf16_t bf16x8 __attribute__((ext_vector_type(8)));
typedef bf16_t bf16x4 __attribute__((ext_vector_type(4)));
typedef bf16_t bf16x2 __attribute__((ext_vector_type(2)));
typedef float f32x4 __attribute__((ext_vector_type(4)));
typedef float f32x16 __attribute__((ext_vector_type(16)));
typedef unsigned int u32x4 __attribute__((ext_vector_type(4)));

#define B_  4
#define S_  2048
#define D_  1024
#define H_  16
#define DK_ 64

// log2(e)/8 : folds the 1/sqrt(64) softmax scale AND ln->log2 conversion into Q.
#define QSCALE 0.18033688011112042f

// async global->LDS, 16B per lane. LDS dest must be wave-uniform base + lane*16.
__device__ __forceinline__ void gload_lds16(const bf16_t* g, bf16_t* l) {
  __builtin_amdgcn_global_load_lds(
      (__attribute__((address_space(1))) void*)(void*)g,
      (__attribute__((address_space(3))) void*)(void*)l,
      16, 0, 0);
}

__device__ __forceinline__ f32x4 mfma_bf16(bf16x8 a, bf16x8 b, f32x4 c) {
  return __builtin_amdgcn_mfma_f32_16x16x32_bf16(a, b, c, 0, 0, 0);
}
__device__ __forceinline__ f32x16 mfma32(bf16x8 a, bf16x8 b, f32x16 c) {
  return __builtin_amdgcn_mfma_f32_32x32x16_bf16(a, b, c, 0, 0, 0);
}

__device__ __forceinline__ unsigned pk2(float a, float b) {
  bf16x2 v; v[0] = (bf16_t)a; v[1] = (bf16_t)b;
  return __builtin_bit_cast(unsigned, v);
}

// v_permlane32_swap_b32: returns {low-halves gathered, high-halves gathered}:
//  out.a = lane<32 ? a(own) : b(lane-32);  out.b = lane<32 ? a(lane+32) : b(own)
__device__ __forceinline__ void pl32(unsigned &a, unsigned &b) {
  auto r = __builtin_amdgcn_permlane32_swap((int)a, (int)b, false, false);
  a = (unsigned)r[0];
  b = (unsigned)r[1];
}

// ---------------- fp32 -> bf16 convert (vectorized) ----------------
__global__ void cvt_f32_bf16(const float* __restrict__ in, bf16_t* __restrict__ out, int n4) {
  int i = blockIdx.x * blockDim.x + threadIdx.x;
  if (i < n4) {
    float4 v = reinterpret_cast<const float4*>(in)[i];
    bf16x4 o;
    o[0] = (bf16_t)v.x; o[1] = (bf16_t)v.y; o[2] = (bf16_t)v.z; o[3] = (bf16_t)v.w;
    reinterpret_cast<bf16x4*>(out)[i] = o;
  }
}

// Fragment-order storage (per head, 131072 elements):
//  Q/K: element (s, dk) -> chunk t=s>>5, d=dk>>4; lane=(s&31)+((dk>>3)&1)*32; e=dk&7
//       idx = ((t*4+d)*64 + lane)*8 + e
//  V:   element (s, dk) -> t=s>>5, tt=(s>>4)&1, j=dk>>5; lane=(dk&31)+((s>>3)&1)*32; e=s&7
//       idx = (((t*2+tt)*2+j)*64 + lane)*8 + e
// attn then loads each MFMA fragment as one fully-coalesced 1KB global_load_dwordx4.

// ---------------- GEMM 1: qkv = x @ Wqkv^T + bqkv, scatter to Q/K/V frags ----------------
// 1D grid 1536 with bijective XCD swizzle: each XCD gets 192 contiguous tiles
// (8 m-panels x 24 n-tiles) -> Wqkv panel reuse in its private L2.
__global__ __launch_bounds__(256) void gemm_qkv(
    const bf16_t* __restrict__ A, const bf16_t* __restrict__ Bm,
    const float* __restrict__ bias,
    bf16_t* __restrict__ Qf, bf16_t* __restrict__ Kf, bf16_t* __restrict__ Vf) {
  __shared__ bf16_t As[128 * 32];
  __shared__ bf16_t Bs[128 * 32];
  const int t = threadIdx.x;
  const int l = t & 63;
  const int w = t >> 6;
  const int wm = w >> 1, wn = w & 1;
  const int fr = l & 15, fh = l >> 4;     // frag row / k-half
  const int bid = (int)blockIdx.x;
  const int swz = (bid & 7) * 192 + (bid >> 3);   // 1536/8 = 192
  const int m0 = (swz / 24) * 128, n0 = (swz % 24) * 128;
  const int K = 1024;
  const int ar = t >> 2, ak = (t & 3) * 8;

  f32x4 acc[4][4] = {};

  for (int k0 = 0; k0 < K; k0 += 32) {
    gload_lds16(A + (size_t)(m0 + ar) * K + k0 + ak,        &As[t * 8]);
    gload_lds16(A + (size_t)(m0 + 64 + ar) * K + k0 + ak,   &As[2048 + t * 8]);
    gload_lds16(Bm + (size_t)(n0 + ar) * K + k0 + ak,       &Bs[t * 8]);
    gload_lds16(Bm + (size_t)(n0 + 64 + ar) * K + k0 + ak,  &Bs[2048 + t * 8]);
    __syncthreads();
    bf16x8 af[4], bfv[4];
#pragma unroll
    for (int i = 0; i < 4; ++i)
      af[i] = *reinterpret_cast<const bf16x8*>(&As[(wm * 64 + i * 16 + fr) * 32 + fh * 8]);
#pragma unroll
    for (int i = 0; i < 4; ++i)
      bfv[i] = *reinterpret_cast<const bf16x8*>(&Bs[(wn * 64 + i * 16 + fr) * 32 + fh * 8]);
#pragma unroll
    for (int mi = 0; mi < 4; ++mi)
#pragma unroll
      for (int ni = 0; ni < 4; ++ni)
        acc[mi][ni] = mfma_bf16(af[mi], bfv[ni], acc[mi][ni]);
    __syncthreads();
  }

#pragma unroll
  for (int mi = 0; mi < 4; ++mi) {
#pragma unroll
    for (int ni = 0; ni < 4; ++ni) {
      const int e = n0 + wn * 64 + ni * 16 + fr;
      const int sec = e >> 10;              // 0=q 1=k 2=v
      const int h = (e & 1023) >> 6, dk = e & 63;
      const float bv = bias[e];
#pragma unroll
      for (int j = 0; j < 4; ++j) {
        const int m = m0 + wm * 64 + mi * 16 + fh * 4 + j;
        const int b = m >> 11, s = m & 2047;
        const float val = acc[mi][ni][j] + bv;
        const size_t hb = (size_t)(b * H_ + h) * (S_ * DK_);
        if (sec == 2) {
          const int tv = s >> 5, tt = (s >> 4) & 1, jj = dk >> 5;
          const int lane = (dk & 31) + ((s >> 3) & 1) * 32, el = s & 7;
          Vf[hb + (size_t)((((tv * 2 + tt) * 2 + jj) * 64 + lane) * 8 + el)] = (bf16_t)val;
        } else {
          const int tq = s >> 5, d = dk >> 4;
          const int lane = (s & 31) + ((dk >> 3) & 1) * 32, el = dk & 7;
          const size_t idx = hb + (size_t)(((tq * 4 + d) * 64 + lane) * 8 + el);
          if (sec == 0) Qf[idx] = (bf16_t)(val * QSCALE);
          else          Kf[idx] = (bf16_t)val;
        }
      }
    }
  }
}

// ---------------- GEMM 2: out = attn_out @ Wout^T + bout (fp32 out) ----------------
// 1D grid 512, XCD swizzle: each XCD gets 64 contiguous tiles (8 m-panels x 8 n-tiles).
__global__ __launch_bounds__(256) void gemm_out(
    const bf16_t* __restrict__ A, const bf16_t* __restrict__ Bm,
    const float* __restrict__ bias, float* __restrict__ out) {
  __shared__ bf16_t As[128 * 32];
  __shared__ bf16_t Bs[128 * 32];
  const int t = threadIdx.x;
  const int l = t & 63;
  const int w = t >> 6;
  const int wm = w >> 1, wn = w & 1;
  const int fr = l & 15, fh = l >> 4;
  const int bid = (int)blockIdx.x;
  const int swz = (bid & 7) * 64 + (bid >> 3);    // 512/8 = 64
  const int m0 = (swz >> 3) * 128, n0 = (swz & 7) * 128;
  const int K = 1024;
  const int ar = t >> 2, ak = (t & 3) * 8;

  f32x4 acc[4][4] = {};

  for (int k0 = 0; k0 < K; k0 += 32) {
    gload_lds16(A + (size_t)(m0 + ar) * K + k0 + ak,        &As[t * 8]);
    gload_lds16(A + (size_t)(m0 + 64 + ar) * K + k0 + ak,   &As[2048 + t * 8]);
    gload_lds16(Bm + (size_t)(n0 + ar) * K + k0 + ak,       &Bs[t * 8]);
    gload_lds16(Bm + (size_t)(n0 + 64 + ar) * K + k0 + ak,  &Bs[2048 + t * 8]);
    __syncthreads();
    bf16x8 af[4], bfv[4];
#pragma unroll
    for (int i = 0; i < 4; ++i)
      af[i] = *reinterpret_cast<const bf16x8*>(&As[(wm * 64 + i * 16 + fr) * 32 + fh * 8]);
#pragma unroll
    for (int i = 0; i < 4; ++i)
      bfv[i] = *reinterpret_cast<const bf16x8*>(&Bs[(wn * 64 + i * 16 + fr) * 32 + fh * 8]);
#pragma unroll
    for (int mi = 0; mi < 4; ++mi)
#pragma unroll
      for (int ni = 0; ni < 4; ++ni)
        acc[mi][ni] = mfma_bf16(af[mi], bfv[ni], acc[mi][ni]);
    __syncthreads();
  }

#pragma unroll
  for (int mi = 0; mi < 4; ++mi) {
#pragma unroll
    for (int ni = 0; ni < 4; ++ni) {
      const int e = n0 + wn * 64 + ni * 16 + fr;
      const float bv = bias[e];
#pragma unroll
      for (int j = 0; j < 4; ++j) {
        const int m = m0 + wm * 64 + mi * 16 + fh * 4 + j;
        out[(size_t)m * D_ + e] = acc[mi][ni][j] + bv;
      }
    }
  }
}

// ---------------- Flash attention: r8 structure + MFMA row-sum (ones trick) ----------------
// grid: 1024 blocks x 256 threads (4 waves). Block = 128 q of one head; wave = 32 q.
// Row-sum moved off the VALU pipe: rs_acc = mfma32(pa, ones) accumulates all 32 row
// sums in 2 extra MFMAs/tile, replacing the 15-add tree AND the epilogue shuffle
// redistribution (rs_acc[r] layout == oa row layout). Max-reduce kept (r7 lesson:
// it also rate-equalizes waves; removing it thrashed L2).
__global__ __launch_bounds__(256, 4) void attn_fwd(
    const bf16_t* __restrict__ Qf, const bf16_t* __restrict__ Kf,
    const bf16_t* __restrict__ Vf, bf16_t* __restrict__ Aout) {
  const int t = threadIdx.x, l = t & 63, w = t >> 6;
  const int lq = l & 31, hi = l >> 5;
  const int bid = (int)blockIdx.x;
  // bijective XCD swizzle: 1024 blocks -> 8 contiguous heads per XCD (K+V 4MB = L2)
  const int swz = (bid & 7) * 128 + (bid >> 3);
  const int bh = swz >> 4;                       // 0..63
  const int q0 = (swz & 15) * 128 + w * 32;      // wave's 32 q-rows
  const int b = bh >> 4, h = bh & 15;

  const bf16_t* Qh = Qf + (size_t)bh * (S_ * DK_);
  const bf16_t* Kh = Kf + (size_t)bh * (S_ * DK_) + (size_t)l * 8;
  const bf16_t* Vh = Vf + (size_t)bh * (S_ * DK_) + (size_t)l * 8;

  // Q frags (coalesced): lane l holds Q[q0+(l&31)][d*16+(l>>5)*8 ..+8]
  const int tq = q0 >> 5;
  bf16x8 qf[4];
#pragma unroll
  for (int d = 0; d < 4; ++d)
    qf[d] = *reinterpret_cast<const bf16x8*>(&Qh[(size_t)(((tq * 4 + d) * 64 + l) * 8)]);

  // ones B-operand for the row-sum MFMA
  bf16x8 ones;
#pragma unroll
  for (int e = 0; e < 8; ++e) ones[e] = (bf16_t)1.0f;

  f32x16 oa0 = {}, oa1 = {};     // O accum: rows q=rowpat(r,hi), cols dk = lq (+32)
  f32x16 rsa = {};               // row-sum accum: rsa[r] = rowsum for q=rowpat(r,hi)
  float m = -1e30f;

  // preload K tile 0
  bf16x8 kA0, kA1, kA2, kA3, kB0, kB1, kB2, kB3;
  kA0 = *reinterpret_cast<const bf16x8*>(&Kh[0 * 512]);
  kA1 = *reinterpret_cast<const bf16x8*>(&Kh[1 * 512]);
  kA2 = *reinterpret_cast<const bf16x8*>(&Kh[2 * 512]);
  kA3 = *reinterpret_cast<const bf16x8*>(&Kh[3 * 512]);

#define ATTN_PHASE(KC0, KC1, KC2, KC3, KN0, KN1, KN2, KN3, CUR, NXT)                      \
  {                                                                                        \
    /* prefetch next tile's K */                                                           \
    KN0 = *reinterpret_cast<const bf16x8*>(&Kh[(size_t)(((NXT) * 4 + 0) * 512)]);          \
    KN1 = *reinterpret_cast<const bf16x8*>(&Kh[(size_t)(((NXT) * 4 + 1) * 512)]);          \
    KN2 = *reinterpret_cast<const bf16x8*>(&Kh[(size_t)(((NXT) * 4 + 2) * 512)]);          \
    KN3 = *reinterpret_cast<const bf16x8*>(&Kh[(size_t)(((NXT) * 4 + 3) * 512)]);          \
    /* current tile's V (used after softmax ~300cyc later) */                              \
    bf16x8 v00 = *reinterpret_cast<const bf16x8*>(&Vh[(size_t)((((CUR) * 2 + 0) * 2 + 0) * 512)]); \
    bf16x8 v01 = *reinterpret_cast<const bf16x8*>(&Vh[(size_t)((((CUR) * 2 + 0) * 2 + 1) * 512)]); \
    bf16x8 v10 = *reinterpret_cast<const bf16x8*>(&Vh[(size_t)((((CUR) * 2 + 1) * 2 + 0) * 512)]); \
    bf16x8 v11 = *reinterpret_cast<const bf16x8*>(&Vh[(size_t)((((CUR) * 2 + 1) * 2 + 1) * 512)]); \
    __builtin_amdgcn_s_setprio(1);                                                         \
    f32x16 cs = {};                                                                        \
    cs = mfma32(KC0, qf[0], cs);                                                           \
    cs = mfma32(KC1, qf[1], cs);                                                           \
    cs = mfma32(KC2, qf[2], cs);                                                           \
    cs = mfma32(KC3, qf[3], cs);                                                           \
    __builtin_amdgcn_s_setprio(0);                                                         \
    /* tile max as max3-friendly triples */                                                \
    float t0 = fmaxf(fmaxf(cs[0], cs[1]), cs[2]);                                          \
    float t1 = fmaxf(fmaxf(cs[3], cs[4]), cs[5]);                                          \
    float t2 = fmaxf(fmaxf(cs[6], cs[7]), cs[8]);                                          \
    float t3 = fmaxf(fmaxf(cs[9], cs[10]), cs[11]);                                        \
    float t4 = fmaxf(fmaxf(cs[12], cs[13]), cs[14]);                                       \
    float tm = fmaxf(fmaxf(fmaxf(t0, t1), cs[15]), fmaxf(fmaxf(t2, t3), t4));              \
    if (__any(tm > m + 8.f)) {                                                             \
      _Pragma("unroll")                                                                    \
      for (int sh = 1; sh < 64; sh <<= 1) tm = fmaxf(tm, __shfl_xor(tm, sh));              \
      const float alpha = __builtin_amdgcn_exp2f(m - tm);                                  \
      m = tm;                                                                              \
      _Pragma("unroll")                                                                    \
      for (int r = 0; r < 16; ++r) { oa0[r] *= alpha; oa1[r] *= alpha; rsa[r] *= alpha; }  \
    }                                                                                      \
    float pv[16];                                                                          \
    _Pragma("unroll")                                                                      \
    for (int r = 0; r < 16; ++r) pv[r] = __builtin_amdgcn_exp2f(cs[r] - m);                \
    _Pragma("unroll")                                                                      \
    for (int tt = 0; tt < 2; ++tt) {                                                       \
      unsigned A0 = pk2(pv[8 * tt],     pv[8 * tt + 1]);                                   \
      unsigned B0 = pk2(pv[8 * tt + 2], pv[8 * tt + 3]);                                   \
      unsigned A1 = pk2(pv[8 * tt + 4], pv[8 * tt + 5]);                                   \
      unsigned B1 = pk2(pv[8 * tt + 6], pv[8 * tt + 7]);                                   \
      pl32(A0, A1);                                                                        \
      pl32(B0, B1);                                                                        \
      u32x4 fw;                                                                            \
      fw[0] = A0; fw[1] = B0; fw[2] = A1; fw[3] = B1;                                      \
      const bf16x8 pa = __builtin_bit_cast(bf16x8, fw);                                    \
      __builtin_amdgcn_s_setprio(1);                                                       \
      oa0 = mfma32(pa, (tt ? v10 : v00), oa0);                                             \
      oa1 = mfma32(pa, (tt ? v11 : v01), oa1);                                             \
      rsa = mfma32(pa, ones, rsa);                                                         \
      __builtin_amdgcn_s_setprio(0);                                                       \
    }                                                                                      \
  }

  for (int it = 0; it < 64; it += 2) {
    ATTN_PHASE(kA0, kA1, kA2, kA3, kB0, kB1, kB2, kB3, it, it + 1)
    ATTN_PHASE(kB0, kB1, kB2, kB3, kA0, kA1, kA2, kA3, it + 1, (it + 2) & 63)
  }
#undef ATTN_PHASE

  // epilogue: rsa[r] already holds the rowsum for q=rowpat(r,hi) -- no shuffles needed
#pragma unroll
  for (int r = 0; r < 16; ++r) {
    const int ql = (r & 3) + 8 * (r >> 2) + 4 * hi;
    const float ir = 1.0f / rsa[r];
    const size_t row = (size_t)(b * S_ + q0 + ql) * D_ + h * 64 + lq;
    Aout[row]      = (bf16_t)(oa0[r] * ir);
    Aout[row + 32] = (bf16_t)(oa1[r] * ir);
  }
}

// ---------------- launch ----------------
extern "C" void kernel_launch(void* const* d_in, const int* in_sizes, int n_in,
                              void* d_out, int out_size, void* d_ws, size_t ws_size,
                              hipStream_t stream) {
  const float* x    = (const float*)d_in[0];
  const float* Wqkv = (const float*)d_in[1];
  const float* bqkv = (const float*)d_in[2];
  const float* Wout = (const float*)d_in[3];
  const float* bout = (const float*)d_in[4];
  float* out = (float*)d_out;

  char* ws = (char*)d_ws;
  bf16_t* xb    = (bf16_t*)(ws);                 // 16 MB
  bf16_t* wqkvb = (bf16_t*)(ws + 16777216);      // 6 MB
  bf16_t* woutb = (bf16_t*)(ws + 23068672);      // 2 MB
  bf16_t* Qfr   = (bf16_t*)(ws + 25165824);      // 16 MB (frag-order, pre-scaled)
  bf16_t* Kfr   = (bf16_t*)(ws + 41943040);      // 16 MB (frag-order)
  bf16_t* Vfr   = (bf16_t*)(ws + 58720256);      // 16 MB (frag-order)
  bf16_t* aout  = (bf16_t*)(ws + 75497472);      // 16 MB

  cvt_f32_bf16<<<8192, 256, 0, stream>>>(x, xb, 2097152);
  cvt_f32_bf16<<<3072, 256, 0, stream>>>(Wqkv, wqkvb, 786432);
  cvt_f32_bf16<<<1024, 256, 0, stream>>>(Wout, woutb, 262144);

  gemm_qkv<<<1536, 256, 0, stream>>>(xb, wqkvb, bqkv, Qfr, Kfr, Vfr);
  attn_fwd<<<1024, 256, 0, stream>>>(Qfr, Kfr, Vfr, aout);
  gemm_out<<<512, 256, 0, stream>>>(aout, woutb, bout, out);
}

// Round 10
// 213.977 us; speedup vs baseline: 1.1805x; 1.1805x over previous
//
#include <hip/hip_runtime.h>
#include <hip/hip_bf16.h>
#include <cstdint>
#include <cstddef>

typedef __bf16 bf16_t;
typedef bf16_t bf16x8 __attribute__((ext_vector_type(8)));
typedef bf16_t bf16x4 __attribute__((ext_vector_type(4)));
typedef bf16_t bf16x2 __attribute__((ext_vector_type(2)));
typedef float f32x4 __attribute__((ext_vector_type(4)));
typedef float f32x16 __attribute__((ext_vector_type(16)));
typedef unsigned int u32x4 __attribute__((ext_vector_type(4)));

#define B_  4
#define S_  2048
#define D_  1024
#define H_  16
#define DK_ 64

// log2(e)/8 : folds the 1/sqrt(64) softmax scale AND ln->log2 conversion into Q.
#define QSCALE 0.18033688011112042f

// async global->LDS, 16B per lane. LDS dest must be wave-uniform base + lane*16.
__device__ __forceinline__ void gload_lds16(const bf16_t* g, bf16_t* l) {
  __builtin_amdgcn_global_load_lds(
      (__attribute__((address_space(1))) void*)(void*)g,
      (__attribute__((address_space(3))) void*)(void*)l,
      16, 0, 0);
}

__device__ __forceinline__ f32x4 mfma_bf16(bf16x8 a, bf16x8 b, f32x4 c) {
  return __builtin_amdgcn_mfma_f32_16x16x32_bf16(a, b, c, 0, 0, 0);
}
__device__ __forceinline__ f32x16 mfma32(bf16x8 a, bf16x8 b, f32x16 c) {
  return __builtin_amdgcn_mfma_f32_32x32x16_bf16(a, b, c, 0, 0, 0);
}

__device__ __forceinline__ unsigned pk2(float a, float b) {
  bf16x2 v; v[0] = (bf16_t)a; v[1] = (bf16_t)b;
  return __builtin_bit_cast(unsigned, v);
}

// v_permlane32_swap_b32: returns {low-halves gathered, high-halves gathered}
__device__ __forceinline__ void pl32(unsigned &a, unsigned &b) {
  auto r = __builtin_amdgcn_permlane32_swap((int)a, (int)b, false, false);
  a = (unsigned)r[0];
  b = (unsigned)r[1];
}

// ---------------- fp32 -> bf16 convert (vectorized) ----------------
__global__ void cvt_f32_bf16(const float* __restrict__ in, bf16_t* __restrict__ out, int n4) {
  int i = blockIdx.x * blockDim.x + threadIdx.x;
  if (i < n4) {
    float4 v = reinterpret_cast<const float4*>(in)[i];
    bf16x4 o;
    o[0] = (bf16_t)v.x; o[1] = (bf16_t)v.y; o[2] = (bf16_t)v.z; o[3] = (bf16_t)v.w;
    reinterpret_cast<bf16x4*>(out)[i] = o;
  }
}

// ================== GEMM skeleton: 128x128 tile, 4-deep K-ring, counted vmcnt ==================
// BK=32, 4 LDS buffers (64 KB). Stage tile kt+3 each iter -> 3 tiles (12 per-wave loads)
// in flight; s_waitcnt vmcnt(12) (counted, never 0 until tail) + RAW s_barrier (no drain).
// LDS swizzle: chunk c' = c ^ ((row>>1)&3) -> 16-lane b128 column reads spread over 8
// four-bank groups (2-way = free). Inverse-swizzled global source, swizzled read.
//
// Staging thread map: ar=t>>2 (row), ac=t&3 (16B chunk); xcol = (ac ^ ((ar>>1)&3))*8.
// Read swizzle (lane-constant): xrd = (fh ^ ((fr>>1)&3))*8.

#define GEMM_STAGE(KT, Aptr, Bptr)                                                          \
  {                                                                                         \
    const int bq_ = (KT) & 3;                                                               \
    gload_lds16((Aptr) + (size_t)(m0 + ar) * 1024 + (KT) * 32 + xcol,      &As[bq_][t * 8]);        \
    gload_lds16((Aptr) + (size_t)(m0 + 64 + ar) * 1024 + (KT) * 32 + xcol, &As[bq_][2048 + t * 8]); \
    gload_lds16((Bptr) + (size_t)(n0 + ar) * 1024 + (KT) * 32 + xcol,      &Bs[bq_][t * 8]);        \
    gload_lds16((Bptr) + (size_t)(n0 + 64 + ar) * 1024 + (KT) * 32 + xcol, &Bs[bq_][2048 + t * 8]); \
  }

#define GEMM_COMPUTE(KT)                                                                    \
  {                                                                                         \
    __builtin_amdgcn_s_barrier();                                                           \
    asm volatile("" ::: "memory");                                                          \
    const bf16_t* Ab_ = &As[(KT) & 3][0];                                                   \
    const bf16_t* Bb_ = &Bs[(KT) & 3][0];                                                   \
    bf16x8 af[4], bfv[4];                                                                   \
    _Pragma("unroll")                                                                       \
    for (int i = 0; i < 4; ++i)                                                             \
      af[i] = *reinterpret_cast<const bf16x8*>(&Ab_[(wm * 64 + i * 16 + fr) * 32 + xrd]);   \
    _Pragma("unroll")                                                                       \
    for (int i = 0; i < 4; ++i)                                                             \
      bfv[i] = *reinterpret_cast<const bf16x8*>(&Bb_[(wn * 64 + i * 16 + fr) * 32 + xrd]);  \
    __builtin_amdgcn_s_setprio(1);                                                          \
    _Pragma("unroll")                                                                       \
    for (int mi = 0; mi < 4; ++mi)                                                          \
      _Pragma("unroll")                                                                     \
      for (int ni = 0; ni < 4; ++ni)                                                        \
        acc[mi][ni] = mfma_bf16(af[mi], bfv[ni], acc[mi][ni]);                              \
    __builtin_amdgcn_s_setprio(0);                                                          \
    asm volatile("" ::: "memory");                                                          \
    __builtin_amdgcn_s_barrier();                                                           \
  }

// ---------------- GEMM 1: qkv = x @ Wqkv^T + bqkv, scatter to Q/K/V frags ----------------
__global__ __launch_bounds__(256, 2) void gemm_qkv(
    const bf16_t* __restrict__ A, const bf16_t* __restrict__ Bm,
    const float* __restrict__ bias,
    bf16_t* __restrict__ Qf, bf16_t* __restrict__ Kf, bf16_t* __restrict__ Vf) {
  __shared__ bf16_t As[4][128 * 32];
  __shared__ bf16_t Bs[4][128 * 32];
  const int t = threadIdx.x;
  const int l = t & 63;
  const int w = t >> 6;
  const int wm = w >> 1, wn = w & 1;
  const int fr = l & 15, fh = l >> 4;
  const int bid = (int)blockIdx.x;
  const int swz = (bid & 7) * 192 + (bid >> 3);   // 1536/8 = 192
  const int m0 = (swz / 24) * 128, n0 = (swz % 24) * 128;
  const int ar = t >> 2;
  const int xcol = (((t & 3) ^ ((ar >> 1) & 3)) * 8);
  const int xrd  = ((fh ^ ((fr >> 1) & 3)) * 8);

  f32x4 acc[4][4] = {};

  GEMM_STAGE(0, A, Bm)
  GEMM_STAGE(1, A, Bm)
  GEMM_STAGE(2, A, Bm)
  for (int kt = 0; kt < 29; ++kt) {
    GEMM_STAGE(kt + 3, A, Bm)
    asm volatile("s_waitcnt vmcnt(12)" ::: "memory");
    GEMM_COMPUTE(kt)
  }
  asm volatile("s_waitcnt vmcnt(8)" ::: "memory");
  GEMM_COMPUTE(29)
  asm volatile("s_waitcnt vmcnt(4)" ::: "memory");
  GEMM_COMPUTE(30)
  asm volatile("s_waitcnt vmcnt(0)" ::: "memory");
  GEMM_COMPUTE(31)

  // epilogue: identical to r8 (verified) — scatter into Q (pre-scaled), K, V frag-order
#pragma unroll
  for (int mi = 0; mi < 4; ++mi) {
#pragma unroll
    for (int ni = 0; ni < 4; ++ni) {
      const int e = n0 + wn * 64 + ni * 16 + fr;
      const int sec = e >> 10;              // 0=q 1=k 2=v
      const int h = (e & 1023) >> 6, dk = e & 63;
      const float bv = bias[e];
#pragma unroll
      for (int j = 0; j < 4; ++j) {
        const int m = m0 + wm * 64 + mi * 16 + fh * 4 + j;
        const int b = m >> 11, s = m & 2047;
        const float val = acc[mi][ni][j] + bv;
        const size_t hb = (size_t)(b * H_ + h) * (S_ * DK_);
        if (sec == 2) {
          const int tv = s >> 5, tt = (s >> 4) & 1, jj = dk >> 5;
          const int lane = (dk & 31) + ((s >> 3) & 1) * 32, el = s & 7;
          Vf[hb + (size_t)((((tv * 2 + tt) * 2 + jj) * 64 + lane) * 8 + el)] = (bf16_t)val;
        } else {
          const int tq = s >> 5, d = dk >> 4;
          const int lane = (s & 31) + ((dk >> 3) & 1) * 32, el = dk & 7;
          const size_t idx = hb + (size_t)(((tq * 4 + d) * 64 + lane) * 8 + el);
          if (sec == 0) Qf[idx] = (bf16_t)(val * QSCALE);
          else          Kf[idx] = (bf16_t)val;
        }
      }
    }
  }
}

// ---------------- GEMM 2: out = attn_out @ Wout^T + bout (fp32 out) ----------------
__global__ __launch_bounds__(256, 2) void gemm_out(
    const bf16_t* __restrict__ A, const bf16_t* __restrict__ Bm,
    const float* __restrict__ bias, float* __restrict__ out) {
  __shared__ bf16_t As[4][128 * 32];
  __shared__ bf16_t Bs[4][128 * 32];
  const int t = threadIdx.x;
  const int l = t & 63;
  const int w = t >> 6;
  const int wm = w >> 1, wn = w & 1;
  const int fr = l & 15, fh = l >> 4;
  const int bid = (int)blockIdx.x;
  const int swz = (bid & 7) * 64 + (bid >> 3);    // 512/8 = 64
  const int m0 = (swz >> 3) * 128, n0 = (swz & 7) * 128;
  const int ar = t >> 2;
  const int xcol = (((t & 3) ^ ((ar >> 1) & 3)) * 8);
  const int xrd  = ((fh ^ ((fr >> 1) & 3)) * 8);

  f32x4 acc[4][4] = {};

  GEMM_STAGE(0, A, Bm)
  GEMM_STAGE(1, A, Bm)
  GEMM_STAGE(2, A, Bm)
  for (int kt = 0; kt < 29; ++kt) {
    GEMM_STAGE(kt + 3, A, Bm)
    asm volatile("s_waitcnt vmcnt(12)" ::: "memory");
    GEMM_COMPUTE(kt)
  }
  asm volatile("s_waitcnt vmcnt(8)" ::: "memory");
  GEMM_COMPUTE(29)
  asm volatile("s_waitcnt vmcnt(4)" ::: "memory");
  GEMM_COMPUTE(30)
  asm volatile("s_waitcnt vmcnt(0)" ::: "memory");
  GEMM_COMPUTE(31)

#pragma unroll
  for (int mi = 0; mi < 4; ++mi) {
#pragma unroll
    for (int ni = 0; ni < 4; ++ni) {
      const int e = n0 + wn * 64 + ni * 16 + fr;
      const float bv = bias[e];
#pragma unroll
      for (int j = 0; j < 4; ++j) {
        const int m = m0 + wm * 64 + mi * 16 + fh * 4 + j;
        out[(size_t)m * D_ + e] = acc[mi][ni][j] + bv;
      }
    }
  }
}

// ---------------- Flash attention: r8 verbatim (94 us verified) ----------------
__global__ __launch_bounds__(256, 4) void attn_fwd(
    const bf16_t* __restrict__ Qf, const bf16_t* __restrict__ Kf,
    const bf16_t* __restrict__ Vf, bf16_t* __restrict__ Aout) {
  const int t = threadIdx.x, l = t & 63, w = t >> 6;
  const int lq = l & 31, hi = l >> 5;
  const int bid = (int)blockIdx.x;
  const int swz = (bid & 7) * 128 + (bid >> 3);
  const int bh = swz >> 4;
  const int q0 = (swz & 15) * 128 + w * 32;
  const int b = bh >> 4, h = bh & 15;

  const bf16_t* Qh = Qf + (size_t)bh * (S_ * DK_);
  const bf16_t* Kh = Kf + (size_t)bh * (S_ * DK_) + (size_t)l * 8;
  const bf16_t* Vh = Vf + (size_t)bh * (S_ * DK_) + (size_t)l * 8;

  const int tq = q0 >> 5;
  bf16x8 qf[4];
#pragma unroll
  for (int d = 0; d < 4; ++d)
    qf[d] = *reinterpret_cast<const bf16x8*>(&Qh[(size_t)(((tq * 4 + d) * 64 + l) * 8)]);

  f32x16 oa0 = {}, oa1 = {};
  float m = -1e30f, rs = 0.f;

  bf16x8 kA0, kA1, kA2, kA3, kB0, kB1, kB2, kB3;
  kA0 = *reinterpret_cast<const bf16x8*>(&Kh[0 * 512]);
  kA1 = *reinterpret_cast<const bf16x8*>(&Kh[1 * 512]);
  kA2 = *reinterpret_cast<const bf16x8*>(&Kh[2 * 512]);
  kA3 = *reinterpret_cast<const bf16x8*>(&Kh[3 * 512]);

#define ATTN_PHASE(KC0, KC1, KC2, KC3, KN0, KN1, KN2, KN3, CUR, NXT)                      \
  {                                                                                        \
    KN0 = *reinterpret_cast<const bf16x8*>(&Kh[(size_t)(((NXT) * 4 + 0) * 512)]);          \
    KN1 = *reinterpret_cast<const bf16x8*>(&Kh[(size_t)(((NXT) * 4 + 1) * 512)]);          \
    KN2 = *reinterpret_cast<const bf16x8*>(&Kh[(size_t)(((NXT) * 4 + 2) * 512)]);          \
    KN3 = *reinterpret_cast<const bf16x8*>(&Kh[(size_t)(((NXT) * 4 + 3) * 512)]);          \
    bf16x8 v00 = *reinterpret_cast<const bf16x8*>(&Vh[(size_t)((((CUR) * 2 + 0) * 2 + 0) * 512)]); \
    bf16x8 v01 = *reinterpret_cast<const bf16x8*>(&Vh[(size_t)((((CUR) * 2 + 0) * 2 + 1) * 512)]); \
    bf16x8 v10 = *reinterpret_cast<const bf16x8*>(&Vh[(size_t)((((CUR) * 2 + 1) * 2 + 0) * 512)]); \
    bf16x8 v11 = *reinterpret_cast<const bf16x8*>(&Vh[(size_t)((((CUR) * 2 + 1) * 2 + 1) * 512)]); \
    __builtin_amdgcn_s_setprio(1);                                                         \
    f32x16 cs = {};                                                                        \
    cs = mfma32(KC0, qf[0], cs);                                                           \
    cs = mfma32(KC1, qf[1], cs);                                                           \
    cs = mfma32(KC2, qf[2], cs);                                                           \
    cs = mfma32(KC3, qf[3], cs);                                                           \
    __builtin_amdgcn_s_setprio(0);                                                         \
    float t0 = fmaxf(fmaxf(cs[0], cs[1]), cs[2]);                                          \
    float t1 = fmaxf(fmaxf(cs[3], cs[4]), cs[5]);                                          \
    float t2 = fmaxf(fmaxf(cs[6], cs[7]), cs[8]);                                          \
    float t3 = fmaxf(fmaxf(cs[9], cs[10]), cs[11]);                                        \
    float t4 = fmaxf(fmaxf(cs[12], cs[13]), cs[14]);                                       \
    float tm = fmaxf(fmaxf(fmaxf(t0, t1), cs[15]), fmaxf(fmaxf(t2, t3), t4));              \
    if (__any(tm > m + 8.f)) {                                                             \
      _Pragma("unroll")                                                                    \
      for (int sh = 1; sh < 64; sh <<= 1) tm = fmaxf(tm, __shfl_xor(tm, sh));              \
      const float alpha = __builtin_amdgcn_exp2f(m - tm);                                  \
      m = tm; rs *= alpha;                                                                 \
      _Pragma("unroll")                                                                    \
      for (int r = 0; r < 16; ++r) { oa0[r] *= alpha; oa1[r] *= alpha; }                   \
    }                                                                                      \
    float pv[16];                                                                          \
    _Pragma("unroll")                                                                      \
    for (int r = 0; r < 16; ++r) pv[r] = __builtin_amdgcn_exp2f(cs[r] - m);                \
    {                                                                                      \
      float s0 = pv[0] + pv[1],   s1 = pv[2] + pv[3];                                      \
      float s2 = pv[4] + pv[5],   s3 = pv[6] + pv[7];                                      \
      float s4 = pv[8] + pv[9],   s5 = pv[10] + pv[11];                                    \
      float s6 = pv[12] + pv[13], s7 = pv[14] + pv[15];                                    \
      rs += ((s0 + s1) + (s2 + s3)) + ((s4 + s5) + (s6 + s7));                             \
    }                                                                                      \
    _Pragma("unroll")                                                                      \
    for (int tt = 0; tt < 2; ++tt) {                                                       \
      unsigned A0 = pk2(pv[8 * tt],     pv[8 * tt + 1]);                                   \
      unsigned B0 = pk2(pv[8 * tt + 2], pv[8 * tt + 3]);                                   \
      unsigned A1 = pk2(pv[8 * tt + 4], pv[8 * tt + 5]);                                   \
      unsigned B1 = pk2(pv[8 * tt + 6], pv[8 * tt + 7]);                                   \
      pl32(A0, A1);                                                                        \
      pl32(B0, B1);                                                                        \
      u32x4 fw;                                                                            \
      fw[0] = A0; fw[1] = B0; fw[2] = A1; fw[3] = B1;                                      \
      const bf16x8 pa = __builtin_bit_cast(bf16x8, fw);                                    \
      __builtin_amdgcn_s_setprio(1);                                                       \
      oa0 = mfma32(pa, (tt ? v10 : v00), oa0);                                             \
      oa1 = mfma32(pa, (tt ? v11 : v01), oa1);                                             \
      __builtin_amdgcn_s_setprio(0);                                                       \
    }                                                                                      \
  }

  for (int it = 0; it < 64; it += 2) {
    ATTN_PHASE(kA0, kA1, kA2, kA3, kB0, kB1, kB2, kB3, it, it + 1)
    ATTN_PHASE(kB0, kB1, kB2, kB3, kA0, kA1, kA2, kA3, it + 1, (it + 2) & 63)
  }
#undef ATTN_PHASE

  rs += __shfl_xor(rs, 32);
  const float inv = 1.0f / rs;
#pragma unroll
  for (int r = 0; r < 16; ++r) {
    const int ql = (r & 3) + 8 * (r >> 2) + 4 * hi;
    const float ir = __shfl(inv, ql);
    const size_t row = (size_t)(b * S_ + q0 + ql) * D_ + h * 64 + lq;
    Aout[row]      = (bf16_t)(oa0[r] * ir);
    Aout[row + 32] = (bf16_t)(oa1[r] * ir);
  }
}

// ---------------- launch ----------------
extern "C" void kernel_launch(void* const* d_in, const int* in_sizes, int n_in,
                              void* d_out, int out_size, void* d_ws, size_t ws_size,
                              hipStream_t stream) {
  const float* x    = (const float*)d_in[0];
  const float* Wqkv = (const float*)d_in[1];
  const float* bqkv = (const float*)d_in[2];
  const float* Wout = (const float*)d_in[3];
  const float* bout = (const float*)d_in[4];
  float* out = (float*)d_out;

  char* ws = (char*)d_ws;
  bf16_t* xb    = (bf16_t*)(ws);                 // 16 MB
  bf16_t* wqkvb = (bf16_t*)(ws + 16777216);      // 6 MB
  bf16_t* woutb = (bf16_t*)(ws + 23068672);      // 2 MB
  bf16_t* Qfr   = (bf16_t*)(ws + 25165824);      // 16 MB (frag-order, pre-scaled)
  bf16_t* Kfr   = (bf16_t*)(ws + 41943040);      // 16 MB (frag-order)
  bf16_t* Vfr   = (bf16_t*)(ws + 58720256);      // 16 MB (frag-order)
  bf16_t* aout  = (bf16_t*)(ws + 75497472);      // 16 MB

  cvt_f32_bf16<<<8192, 256, 0, stream>>>(x, xb, 2097152);
  cvt_f32_bf16<<<3072, 256, 0, stream>>>(Wqkv, wqkvb, 786432);
  cvt_f32_bf16<<<1024, 256, 0, stream>>>(Wout, woutb, 262144);

  gemm_qkv<<<1536, 256, 0, stream>>>(xb, wqkvb, bqkv, Qfr, Kfr, Vfr);
  attn_fwd<<<1024, 256, 0, stream>>>(Qfr, Kfr, Vfr, aout);
  gemm_out<<<512, 256, 0, stream>>>(aout, woutb, bout, out);
}

// Round 11
// 200.555 us; speedup vs baseline: 1.2595x; 1.0669x over previous
//
#include <hip/hip_runtime.h>
#include <hip/hip_bf16.h>
#include <cstdint>
#include <cstddef>

typedef __bf16 bf16_t;
typedef bf16_t bf16x8 __attribute__((ext_vector_type(8)));
typedef bf16_t bf16x4 __attribute__((ext_vector_type(4)));
typedef bf16_t bf16x2 __attribute__((ext_vector_type(2)));
typedef float f32x4 __attribute__((ext_vector_type(4)));
typedef float f32x16 __attribute__((ext_vector_type(16)));
typedef unsigned int u32x4 __attribute__((ext_vector_type(4)));

#define B_  4
#define S_  2048
#define D_  1024
#define H_  16
#define DK_ 64

// log2(e)/8 : folds the 1/sqrt(64) softmax scale AND ln->log2 conversion into Q.
#define QSCALE 0.18033688011112042f

// async global->LDS, 16B per lane. LDS dest must be wave-uniform base + lane*16.
__device__ __forceinline__ void gload_lds16(const bf16_t* g, bf16_t* l) {
  __builtin_amdgcn_global_load_lds(
      (__attribute__((address_space(1))) void*)(void*)g,
      (__attribute__((address_space(3))) void*)(void*)l,
      16, 0, 0);
}

__device__ __forceinline__ f32x4 mfma_bf16(bf16x8 a, bf16x8 b, f32x4 c) {
  return __builtin_amdgcn_mfma_f32_16x16x32_bf16(a, b, c, 0, 0, 0);
}
__device__ __forceinline__ f32x16 mfma32(bf16x8 a, bf16x8 b, f32x16 c) {
  return __builtin_amdgcn_mfma_f32_32x32x16_bf16(a, b, c, 0, 0, 0);
}

__device__ __forceinline__ unsigned pk2(float a, float b) {
  bf16x2 v; v[0] = (bf16_t)a; v[1] = (bf16_t)b;
  return __builtin_bit_cast(unsigned, v);
}

// v_permlane32_swap_b32: returns {low-halves gathered, high-halves gathered}
__device__ __forceinline__ void pl32(unsigned &a, unsigned &b) {
  auto r = __builtin_amdgcn_permlane32_swap((int)a, (int)b, false, false);
  a = (unsigned)r[0];
  b = (unsigned)r[1];
}

// ---------------- fused fp32 -> bf16 convert: x | Wqkv | Wout in one launch ----------------
#define NQ_X  2097152   // x quads
#define NQ_WQ  786432   // Wqkv quads
#define NQ_WO  262144   // Wout quads
__global__ void cvt_all(const float* __restrict__ x, const float* __restrict__ wq,
                        const float* __restrict__ wo,
                        bf16_t* __restrict__ xb, bf16_t* __restrict__ wqb,
                        bf16_t* __restrict__ wob) {
  int i = blockIdx.x * blockDim.x + threadIdx.x;   // quad index over concatenated space
  const float* src;
  bf16_t* dst;
  if (i < NQ_X)                  { src = x;  dst = xb; }
  else if (i < NQ_X + NQ_WQ)     { src = wq; dst = wqb; i -= NQ_X; }
  else if (i < NQ_X + NQ_WQ + NQ_WO) { src = wo; dst = wob; i -= (NQ_X + NQ_WQ); }
  else return;
  float4 v = reinterpret_cast<const float4*>(src)[i];
  bf16x4 o;
  o[0] = (bf16_t)v.x; o[1] = (bf16_t)v.y; o[2] = (bf16_t)v.z; o[3] = (bf16_t)v.w;
  reinterpret_cast<bf16x4*>(dst)[i] = o;
}

// Fragment-order storage (per head, 131072 elements):
//  Q/K: element (s, dk) -> chunk t=s>>5, d=dk>>4; lane=(s&31)+((dk>>3)&1)*32; e=dk&7
//       idx = ((t*4+d)*64 + lane)*8 + e
//  V:   element (s, dk) -> t=s>>5, tt=(s>>4)&1, j=dk>>5; lane=(dk&31)+((s>>3)&1)*32; e=s&7
//       idx = (((t*2+tt)*2+j)*64 + lane)*8 + e
// attn then loads each MFMA fragment as one fully-coalesced 1KB global_load_dwordx4.

// ---------------- GEMM 1: qkv = x @ Wqkv^T + bqkv, scatter to Q/K/V frags ----------------
// r8-verbatim m97 structure (verified ~57us). 1D grid 1536, bijective XCD swizzle.
__global__ __launch_bounds__(256) void gemm_qkv(
    const bf16_t* __restrict__ A, const bf16_t* __restrict__ Bm,
    const float* __restrict__ bias,
    bf16_t* __restrict__ Qf, bf16_t* __restrict__ Kf, bf16_t* __restrict__ Vf) {
  __shared__ bf16_t As[128 * 32];
  __shared__ bf16_t Bs[128 * 32];
  const int t = threadIdx.x;
  const int l = t & 63;
  const int w = t >> 6;
  const int wm = w >> 1, wn = w & 1;
  const int fr = l & 15, fh = l >> 4;     // frag row / k-half
  const int bid = (int)blockIdx.x;
  const int swz = (bid & 7) * 192 + (bid >> 3);   // 1536/8 = 192
  const int m0 = (swz / 24) * 128, n0 = (swz % 24) * 128;
  const int K = 1024;
  const int ar = t >> 2, ak = (t & 3) * 8;

  f32x4 acc[4][4] = {};

  for (int k0 = 0; k0 < K; k0 += 32) {
    gload_lds16(A + (size_t)(m0 + ar) * K + k0 + ak,        &As[t * 8]);
    gload_lds16(A + (size_t)(m0 + 64 + ar) * K + k0 + ak,   &As[2048 + t * 8]);
    gload_lds16(Bm + (size_t)(n0 + ar) * K + k0 + ak,       &Bs[t * 8]);
    gload_lds16(Bm + (size_t)(n0 + 64 + ar) * K + k0 + ak,  &Bs[2048 + t * 8]);
    __syncthreads();
    bf16x8 af[4], bfv[4];
#pragma unroll
    for (int i = 0; i < 4; ++i)
      af[i] = *reinterpret_cast<const bf16x8*>(&As[(wm * 64 + i * 16 + fr) * 32 + fh * 8]);
#pragma unroll
    for (int i = 0; i < 4; ++i)
      bfv[i] = *reinterpret_cast<const bf16x8*>(&Bs[(wn * 64 + i * 16 + fr) * 32 + fh * 8]);
#pragma unroll
    for (int mi = 0; mi < 4; ++mi)
#pragma unroll
      for (int ni = 0; ni < 4; ++ni)
        acc[mi][ni] = mfma_bf16(af[mi], bfv[ni], acc[mi][ni]);
    __syncthreads();
  }

#pragma unroll
  for (int mi = 0; mi < 4; ++mi) {
#pragma unroll
    for (int ni = 0; ni < 4; ++ni) {
      const int e = n0 + wn * 64 + ni * 16 + fr;
      const int sec = e >> 10;              // 0=q 1=k 2=v
      const int h = (e & 1023) >> 6, dk = e & 63;
      const float bv = bias[e];
#pragma unroll
      for (int j = 0; j < 4; ++j) {
        const int m = m0 + wm * 64 + mi * 16 + fh * 4 + j;
        const int b = m >> 11, s = m & 2047;
        const float val = acc[mi][ni][j] + bv;
        const size_t hb = (size_t)(b * H_ + h) * (S_ * DK_);
        if (sec == 2) {
          const int tv = s >> 5, tt = (s >> 4) & 1, jj = dk >> 5;
          const int lane = (dk & 31) + ((s >> 3) & 1) * 32, el = s & 7;
          Vf[hb + (size_t)((((tv * 2 + tt) * 2 + jj) * 64 + lane) * 8 + el)] = (bf16_t)val;
        } else {
          const int tq = s >> 5, d = dk >> 4;
          const int lane = (s & 31) + ((dk >> 3) & 1) * 32, el = dk & 7;
          const size_t idx = hb + (size_t)(((tq * 4 + d) * 64 + lane) * 8 + el);
          if (sec == 0) Qf[idx] = (bf16_t)(val * QSCALE);
          else          Kf[idx] = (bf16_t)val;
        }
      }
    }
  }
}

// ---------------- GEMM 2: out = attn_out @ Wout^T + bout (fp32 out) ----------------
// r8-verbatim m97 structure. 1D grid 512, XCD swizzle.
__global__ __launch_bounds__(256) void gemm_out(
    const bf16_t* __restrict__ A, const bf16_t* __restrict__ Bm,
    const float* __restrict__ bias, float* __restrict__ out) {
  __shared__ bf16_t As[128 * 32];
  __shared__ bf16_t Bs[128 * 32];
  const int t = threadIdx.x;
  const int l = t & 63;
  const int w = t >> 6;
  const int wm = w >> 1, wn = w & 1;
  const int fr = l & 15, fh = l >> 4;
  const int bid = (int)blockIdx.x;
  const int swz = (bid & 7) * 64 + (bid >> 3);    // 512/8 = 64
  const int m0 = (swz >> 3) * 128, n0 = (swz & 7) * 128;
  const int K = 1024;
  const int ar = t >> 2, ak = (t & 3) * 8;

  f32x4 acc[4][4] = {};

  for (int k0 = 0; k0 < K; k0 += 32) {
    gload_lds16(A + (size_t)(m0 + ar) * K + k0 + ak,        &As[t * 8]);
    gload_lds16(A + (size_t)(m0 + 64 + ar) * K + k0 + ak,   &As[2048 + t * 8]);
    gload_lds16(Bm + (size_t)(n0 + ar) * K + k0 + ak,       &Bs[t * 8]);
    gload_lds16(Bm + (size_t)(n0 + 64 + ar) * K + k0 + ak,  &Bs[2048 + t * 8]);
    __syncthreads();
    bf16x8 af[4], bfv[4];
#pragma unroll
    for (int i = 0; i < 4; ++i)
      af[i] = *reinterpret_cast<const bf16x8*>(&As[(wm * 64 + i * 16 + fr) * 32 + fh * 8]);
#pragma unroll
    for (int i = 0; i < 4; ++i)
      bfv[i] = *reinterpret_cast<const bf16x8*>(&Bs[(wn * 64 + i * 16 + fr) * 32 + fh * 8]);
#pragma unroll
    for (int mi = 0; mi < 4; ++mi)
#pragma unroll
      for (int ni = 0; ni < 4; ++ni)
        acc[mi][ni] = mfma_bf16(af[mi], bfv[ni], acc[mi][ni]);
    __syncthreads();
  }

#pragma unroll
  for (int mi = 0; mi < 4; ++mi) {
#pragma unroll
    for (int ni = 0; ni < 4; ++ni) {
      const int e = n0 + wn * 64 + ni * 16 + fr;
      const float bv = bias[e];
#pragma unroll
      for (int j = 0; j < 4; ++j) {
        const int m = m0 + wm * 64 + mi * 16 + fh * 4 + j;
        out[(size_t)m * D_ + e] = acc[mi][ni][j] + bv;
      }
    }
  }
}

// ---------------- Flash attention: r8 verbatim (94 us verified) ----------------
__global__ __launch_bounds__(256, 4) void attn_fwd(
    const bf16_t* __restrict__ Qf, const bf16_t* __restrict__ Kf,
    const bf16_t* __restrict__ Vf, bf16_t* __restrict__ Aout) {
  const int t = threadIdx.x, l = t & 63, w = t >> 6;
  const int lq = l & 31, hi = l >> 5;
  const int bid = (int)blockIdx.x;
  const int swz = (bid & 7) * 128 + (bid >> 3);
  const int bh = swz >> 4;
  const int q0 = (swz & 15) * 128 + w * 32;
  const int b = bh >> 4, h = bh & 15;

  const bf16_t* Qh = Qf + (size_t)bh * (S_ * DK_);
  const bf16_t* Kh = Kf + (size_t)bh * (S_ * DK_) + (size_t)l * 8;
  const bf16_t* Vh = Vf + (size_t)bh * (S_ * DK_) + (size_t)l * 8;

  const int tq = q0 >> 5;
  bf16x8 qf[4];
#pragma unroll
  for (int d = 0; d < 4; ++d)
    qf[d] = *reinterpret_cast<const bf16x8*>(&Qh[(size_t)(((tq * 4 + d) * 64 + l) * 8)]);

  f32x16 oa0 = {}, oa1 = {};
  float m = -1e30f, rs = 0.f;

  bf16x8 kA0, kA1, kA2, kA3, kB0, kB1, kB2, kB3;
  kA0 = *reinterpret_cast<const bf16x8*>(&Kh[0 * 512]);
  kA1 = *reinterpret_cast<const bf16x8*>(&Kh[1 * 512]);
  kA2 = *reinterpret_cast<const bf16x8*>(&Kh[2 * 512]);
  kA3 = *reinterpret_cast<const bf16x8*>(&Kh[3 * 512]);

#define ATTN_PHASE(KC0, KC1, KC2, KC3, KN0, KN1, KN2, KN3, CUR, NXT)                      \
  {                                                                                        \
    KN0 = *reinterpret_cast<const bf16x8*>(&Kh[(size_t)(((NXT) * 4 + 0) * 512)]);          \
    KN1 = *reinterpret_cast<const bf16x8*>(&Kh[(size_t)(((NXT) * 4 + 1) * 512)]);          \
    KN2 = *reinterpret_cast<const bf16x8*>(&Kh[(size_t)(((NXT) * 4 + 2) * 512)]);          \
    KN3 = *reinterpret_cast<const bf16x8*>(&Kh[(size_t)(((NXT) * 4 + 3) * 512)]);          \
    bf16x8 v00 = *reinterpret_cast<const bf16x8*>(&Vh[(size_t)((((CUR) * 2 + 0) * 2 + 0) * 512)]); \
    bf16x8 v01 = *reinterpret_cast<const bf16x8*>(&Vh[(size_t)((((CUR) * 2 + 0) * 2 + 1) * 512)]); \
    bf16x8 v10 = *reinterpret_cast<const bf16x8*>(&Vh[(size_t)((((CUR) * 2 + 1) * 2 + 0) * 512)]); \
    bf16x8 v11 = *reinterpret_cast<const bf16x8*>(&Vh[(size_t)((((CUR) * 2 + 1) * 2 + 1) * 512)]); \
    __builtin_amdgcn_s_setprio(1);                                                         \
    f32x16 cs = {};                                                                        \
    cs = mfma32(KC0, qf[0], cs);                                                           \
    cs = mfma32(KC1, qf[1], cs);                                                           \
    cs = mfma32(KC2, qf[2], cs);                                                           \
    cs = mfma32(KC3, qf[3], cs);                                                           \
    __builtin_amdgcn_s_setprio(0);                                                         \
    float t0 = fmaxf(fmaxf(cs[0], cs[1]), cs[2]);                                          \
    float t1 = fmaxf(fmaxf(cs[3], cs[4]), cs[5]);                                          \
    float t2 = fmaxf(fmaxf(cs[6], cs[7]), cs[8]);                                          \
    float t3 = fmaxf(fmaxf(cs[9], cs[10]), cs[11]);                                        \
    float t4 = fmaxf(fmaxf(cs[12], cs[13]), cs[14]);                                       \
    float tm = fmaxf(fmaxf(fmaxf(t0, t1), cs[15]), fmaxf(fmaxf(t2, t3), t4));              \
    if (__any(tm > m + 8.f)) {                                                             \
      _Pragma("unroll")                                                                    \
      for (int sh = 1; sh < 64; sh <<= 1) tm = fmaxf(tm, __shfl_xor(tm, sh));              \
      const float alpha = __builtin_amdgcn_exp2f(m - tm);                                  \
      m = tm; rs *= alpha;                                                                 \
      _Pragma("unroll")                                                                    \
      for (int r = 0; r < 16; ++r) { oa0[r] *= alpha; oa1[r] *= alpha; }                   \
    }                                                                                      \
    float pv[16];                                                                          \
    _Pragma("unroll")                                                                      \
    for (int r = 0; r < 16; ++r) pv[r] = __builtin_amdgcn_exp2f(cs[r] - m);                \
    {                                                                                      \
      float s0 = pv[0] + pv[1],   s1 = pv[2] + pv[3];                                      \
      float s2 = pv[4] + pv[5],   s3 = pv[6] + pv[7];                                      \
      float s4 = pv[8] + pv[9],   s5 = pv[10] + pv[11];                                    \
      float s6 = pv[12] + pv[13], s7 = pv[14] + pv[15];                                    \
      rs += ((s0 + s1) + (s2 + s3)) + ((s4 + s5) + (s6 + s7));                             \
    }                                                                                      \
    _Pragma("unroll")                                                                      \
    for (int tt = 0; tt < 2; ++tt) {                                                       \
      unsigned A0 = pk2(pv[8 * tt],     pv[8 * tt + 1]);                                   \
      unsigned B0 = pk2(pv[8 * tt + 2], pv[8 * tt + 3]);                                   \
      unsigned A1 = pk2(pv[8 * tt + 4], pv[8 * tt + 5]);                                   \
      unsigned B1 = pk2(pv[8 * tt + 6], pv[8 * tt + 7]);                                   \
      pl32(A0, A1);                                                                        \
      pl32(B0, B1);                                                                        \
      u32x4 fw;                                                                            \
      fw[0] = A0; fw[1] = B0; fw[2] = A1; fw[3] = B1;                                      \
      const bf16x8 pa = __builtin_bit_cast(bf16x8, fw);                                    \
      __builtin_amdgcn_s_setprio(1);                                                       \
      oa0 = mfma32(pa, (tt ? v10 : v00), oa0);                                             \
      oa1 = mfma32(pa, (tt ? v11 : v01), oa1);                                             \
      __builtin_amdgcn_s_setprio(0);                                                       \
    }                                                                                      \
  }

  for (int it = 0; it < 64; it += 2) {
    ATTN_PHASE(kA0, kA1, kA2, kA3, kB0, kB1, kB2, kB3, it, it + 1)
    ATTN_PHASE(kB0, kB1, kB2, kB3, kA0, kA1, kA2, kA3, it + 1, (it + 2) & 63)
  }
#undef ATTN_PHASE

  rs += __shfl_xor(rs, 32);
  const float inv = 1.0f / rs;
#pragma unroll
  for (int r = 0; r < 16; ++r) {
    const int ql = (r & 3) + 8 * (r >> 2) + 4 * hi;
    const float ir = __shfl(inv, ql);
    const size_t row = (size_t)(b * S_ + q0 + ql) * D_ + h * 64 + lq;
    Aout[row]      = (bf16_t)(oa0[r] * ir);
    Aout[row + 32] = (bf16_t)(oa1[r] * ir);
  }
}

// ---------------- launch ----------------
extern "C" void kernel_launch(void* const* d_in, const int* in_sizes, int n_in,
                              void* d_out, int out_size, void* d_ws, size_t ws_size,
                              hipStream_t stream) {
  const float* x    = (const float*)d_in[0];
  const float* Wqkv = (const float*)d_in[1];
  const float* bqkv = (const float*)d_in[2];
  const float* Wout = (const float*)d_in[3];
  const float* bout = (const float*)d_in[4];
  float* out = (float*)d_out;

  char* ws = (char*)d_ws;
  bf16_t* xb    = (bf16_t*)(ws);                 // 16 MB
  bf16_t* wqkvb = (bf16_t*)(ws + 16777216);      // 6 MB
  bf16_t* woutb = (bf16_t*)(ws + 23068672);      // 2 MB
  bf16_t* Qfr   = (bf16_t*)(ws + 25165824);      // 16 MB (frag-order, pre-scaled)
  bf16_t* Kfr   = (bf16_t*)(ws + 41943040);      // 16 MB (frag-order)
  bf16_t* Vfr   = (bf16_t*)(ws + 58720256);      // 16 MB (frag-order)
  bf16_t* aout  = (bf16_t*)(ws + 75497472);      // 16 MB

  cvt_all<<<12288, 256, 0, stream>>>(x, Wqkv, Wout, xb, wqkvb, woutb);

  gemm_qkv<<<1536, 256, 0, stream>>>(xb, wqkvb, bqkv, Qfr, Kfr, Vfr);
  attn_fwd<<<1024, 256, 0, stream>>>(Qfr, Kfr, Vfr, aout);
  gemm_out<<<512, 256, 0, stream>>>(aout, woutb, bout, out);
}